// Round 7
// baseline (235.769 us; speedup 1.0000x reference)
//
#include <hip/hip_runtime.h>

#define H 128
#define NHEADS 8
#define SQ 4096
#define HD 1024   // NHEADS*H

typedef float f32x4 __attribute__((ext_vector_type(4)));
typedef __bf16 bf16x8 __attribute__((ext_vector_type(8)));
typedef unsigned short u16x4 __attribute__((ext_vector_type(4)));
typedef unsigned short u16x8 __attribute__((ext_vector_type(8)));

static __device__ __forceinline__ unsigned short f2bf(float f) {
  unsigned int u = __builtin_bit_cast(unsigned int, f);
  u += 0x7fffu + ((u >> 16) & 1u);           // round-nearest-even
  return (unsigned short)(u >> 16);
}

static __device__ __forceinline__ bf16x8 ld_bf8(const unsigned short* p) {
  return __builtin_bit_cast(bf16x8, *(const u16x8*)p);
}

// ---------------- kernel 0: weight transpose+convert (R5 verbatim) --------
__global__ __launch_bounds__(256) void prep_kernel(
    const float* __restrict__ W1, const float* __restrict__ W2,
    const float* __restrict__ Wc,
    unsigned short* __restrict__ W1T, unsigned short* __restrict__ W2T,
    unsigned short* __restrict__ WcT)
{
  int t = blockIdx.x * 256 + threadIdx.x;
  if (t < HD * H) {
    {
      int n = t / H, k = t % H;              // W1/W2 are [128 k][1024 n]
      W1T[t] = f2bf(W1[k * HD + n]);
      W2T[t] = f2bf(W2[k * HD + n]);
    }
    {
      int n = t / HD, k = t % HD;            // Wc is [1024 k][128 n]
      WcT[t] = f2bf(Wc[k * H + n]);
    }
  }
}

// ---------------- kernel 1: q1/q2 projection (R5 verbatim) ----------------
__global__ __launch_bounds__(256) void proj_kernel(
    const float* __restrict__ x,
    const float* __restrict__ b1, const float* __restrict__ b2,
    const unsigned short* __restrict__ W1T, const unsigned short* __restrict__ W2T,
    unsigned short* __restrict__ q1bf, unsigned short* __restrict__ q2K,
    unsigned short* __restrict__ q2VT)
{
  __shared__ unsigned short At[64 * 136];
  __shared__ unsigned short Bt[128 * 136];
  const int tid = threadIdx.x;
  const int st = blockIdx.x & 63, h = blockIdx.x >> 6;
  const int s0 = st * 64;
  const int lane = tid & 63, w = tid >> 6;
  const int c = lane & 15, q4 = lane >> 4;

  for (int i = 0; i < 4; ++i) {
    int ch = tid + i * 256;
    int row = ch >> 4, col8 = (ch & 15) * 8;
    const float* gp = x + (s0 + row) * H + col8;
    f32x4 a = *(const f32x4*)gp;
    f32x4 b = *(const f32x4*)(gp + 4);
    u16x8 v;
    v[0]=f2bf(a[0]); v[1]=f2bf(a[1]); v[2]=f2bf(a[2]); v[3]=f2bf(a[3]);
    v[4]=f2bf(b[0]); v[5]=f2bf(b[1]); v[6]=f2bf(b[2]); v[7]=f2bf(b[3]);
    *(u16x8*)&At[row * 136 + col8] = v;
  }
  for (int i = 0; i < 8; ++i) {
    int ch = tid + i * 256;
    int row = ch >> 4, col8 = (ch & 15) * 8;
    *(u16x8*)&Bt[row * 136 + col8] = *(const u16x8*)&W1T[(h * H + row) * H + col8];
  }
  __syncthreads();

  bf16x8 af[4];
  for (int kc = 0; kc < 4; ++kc)
    af[kc] = ld_bf8(&At[(w * 16 + c) * 136 + kc * 32 + q4 * 8]);

  for (int nt = 0; nt < 8; ++nt) {
    f32x4 acc = {0.f, 0.f, 0.f, 0.f};
    for (int kc = 0; kc < 4; ++kc) {
      bf16x8 bf = ld_bf8(&Bt[(nt * 16 + c) * 136 + kc * 32 + q4 * 8]);
      acc = __builtin_amdgcn_mfma_f32_16x16x32_bf16(af[kc], bf, acc, 0, 0, 0);
    }
    float bb = b1[h * H + nt * 16 + c];
    for (int r = 0; r < 4; ++r) {
      int srow = s0 + w * 16 + q4 * 4 + r;
      q1bf[(h * SQ + srow) * H + nt * 16 + c] = f2bf(acc[r] + bb);
    }
  }
  __syncthreads();
  for (int i = 0; i < 8; ++i) {
    int ch = tid + i * 256;
    int row = ch >> 4, col8 = (ch & 15) * 8;
    *(u16x8*)&Bt[row * 136 + col8] = *(const u16x8*)&W2T[(h * H + row) * H + col8];
  }
  __syncthreads();
  for (int nt = 0; nt < 8; ++nt) {
    f32x4 acc = {0.f, 0.f, 0.f, 0.f};
    for (int kc = 0; kc < 4; ++kc) {
      bf16x8 bf = ld_bf8(&Bt[(nt * 16 + c) * 136 + kc * 32 + q4 * 8]);
      acc = __builtin_amdgcn_mfma_f32_16x16x32_bf16(af[kc], bf, acc, 0, 0, 0);
    }
    float bb = b2[h * H + nt * 16 + c];
    unsigned short vs[4];
    for (int r = 0; r < 4; ++r) {
      int srow = s0 + w * 16 + q4 * 4 + r;
      unsigned short u = f2bf(acc[r] + bb);
      q2K[(h * SQ + srow) * H + nt * 16 + c] = u;
      vs[r] = u;
    }
    u16x4 v4 = {vs[0], vs[1], vs[2], vs[3]};
    *(u16x4*)&q2VT[(h * H + nt * 16 + c) * SQ + s0 + w * 16 + q4 * 4] = v4;
  }
}

// ---------------- kernel 2: flash attention, D-SPLIT ----------------
// grid 512 = db(2) x 8 heads x 32 q-blocks of 128 rows -> 2 blocks/CU
// (2 waves/SIMD latency hiding; R5 was 1). Block db recomputes the FULL
// S^T/exp/l (duplicated -- cheap) but runs PV and the ctx store only for
// its 64 output d-columns (nt = db*4 .. db*4+3). Outputs are disjoint:
// NO combine, NO extra workspace, numerics per column identical to R5
// (same op order in both blocks -> identical l). All layouts/pitches are
// R5-verbatim (152 / 88 / 72). LDS 60416 B; 2 blocks/CU = 120832 < 160K.
__global__ __launch_bounds__(256) void flash_kernel(
    const unsigned short* __restrict__ q1bf,
    const unsigned short* __restrict__ q2K,
    const unsigned short* __restrict__ q2VT,
    unsigned short* __restrict__ ctxbf)
{
  __shared__ unsigned short Kt[64 * 152];      // [key][d]  pitch 152
  __shared__ unsigned short VT[128 * 88];      // [d][key]  pitch 88
  __shared__ unsigned short Pb[4][2][16 * 72]; // per-wave/per-qblk [q][key]
  const int tid = threadIdx.x;
  const int bid = blockIdx.x;
  const int db = bid >> 8;                     // output d-half
  const int h = (bid >> 5) & 7, qb = bid & 31;
  const int s0 = qb * 128;
  const int lane = tid & 63, w = tid >> 6;
  const int c = lane & 15, q4 = lane >> 4;

  // hoist Q B-frags for both q-blocks: B[k = kc*32 + q4*8 + j][n = q = c]
  bf16x8 qf[2][4];
  for (int blk = 0; blk < 2; ++blk)
    for (int kc = 0; kc < 4; ++kc)
      qf[blk][kc] = ld_bf8(
          &q1bf[(h * SQ + s0 + w * 32 + blk * 16 + c) * H + kc * 32 + q4 * 8]);

  f32x4 acc[2][4];                             // only 4 nt-tiles (our d-half)
  for (int blk = 0; blk < 2; ++blk)
    for (int nt = 0; nt < 4; ++nt) acc[blk][nt] = (f32x4){0.f, 0.f, 0.f, 0.f};
  float lsum[2] = {0.f, 0.f};

  // prefetch tile 0 into registers
  u16x8 kreg[4], vreg[4];
  for (int i = 0; i < 4; ++i) {
    int ch = tid + i * 256;
    kreg[i] = *(const u16x8*)&q2K[(h * SQ + (ch >> 4)) * H + (ch & 15) * 8];
    vreg[i] = *(const u16x8*)&q2VT[(h * H + (ch >> 3)) * SQ + (ch & 7) * 8];
  }

  for (int kt = 0; kt < 64; ++kt) {
    if (kt) __syncthreads();               // prev-iter readers done
    for (int i = 0; i < 4; ++i) {          // regs -> LDS
      int ch = tid + i * 256;
      *(u16x8*)&Kt[(ch >> 4) * 152 + (ch & 15) * 8] = kreg[i];
      *(u16x8*)&VT[(ch >> 3) * 88 + (ch & 7) * 8] = vreg[i];
    }
    __syncthreads();                       // staging visible

    if (kt < 63) {                         // prefetch next tile -> regs
      const int k0 = (kt + 1) * 64;
      for (int i = 0; i < 4; ++i) {
        int ch = tid + i * 256;
        kreg[i] = *(const u16x8*)&q2K[(h * SQ + k0 + (ch >> 4)) * H + (ch & 15) * 8];
        vreg[i] = *(const u16x8*)&q2VT[(h * H + (ch >> 3)) * SQ + k0 + (ch & 7) * 8];
      }
    }

    // S^T = K.Q^T per q-block (FULL, duplicated across db):
    // C[key = mt*16 + q4*4 + r][q = c]
    f32x4 sc[2][4];
    for (int mt = 0; mt < 4; ++mt) {
      bf16x8 kf[4];
      for (int kc = 0; kc < 4; ++kc)
        kf[kc] = ld_bf8(&Kt[(mt * 16 + c) * 152 + kc * 32 + q4 * 8]);
      for (int blk = 0; blk < 2; ++blk) {
        f32x4 s = {0.f, 0.f, 0.f, 0.f};
        for (int kc = 0; kc < 4; ++kc)
          s = __builtin_amdgcn_mfma_f32_16x16x32_bf16(kf[kc], qf[blk][kc], s, 0, 0, 0);
        sc[blk][mt] = s;
      }
    }

    // p = exp(s); per-lane partial l; write P row-major [q = c][key]
    for (int blk = 0; blk < 2; ++blk) {
      float ts = 0.f;
      for (int mt = 0; mt < 4; ++mt) {
        f32x4 p;
        for (int r = 0; r < 4; ++r) { p[r] = __expf(sc[blk][mt][r]); ts += p[r]; }
        sc[blk][mt] = p;
      }
      lsum[blk] += ts;
      for (int mt = 0; mt < 4; ++mt) {
        u16x4 pv = {f2bf(sc[blk][mt][0]), f2bf(sc[blk][mt][1]),
                    f2bf(sc[blk][mt][2]), f2bf(sc[blk][mt][3])};
        *(u16x4*)&Pb[w][blk][c * 72 + mt * 16 + q4 * 4] = pv;
      }
    }

    // PV (our d-half only): acc[blk][nt] += P[q][key32] . V[key32][d]
    for (int kc2 = 0; kc2 < 2; ++kc2) {
      bf16x8 pf0 = ld_bf8(&Pb[w][0][c * 72 + kc2 * 32 + q4 * 8]);
      bf16x8 pf1 = ld_bf8(&Pb[w][1][c * 72 + kc2 * 32 + q4 * 8]);
      for (int nt = 0; nt < 4; ++nt) {
        int ntg = db * 4 + nt;
        bf16x8 vf = ld_bf8(&VT[(ntg * 16 + c) * 88 + kc2 * 32 + q4 * 8]);
        acc[0][nt] = __builtin_amdgcn_mfma_f32_16x16x32_bf16(pf0, vf, acc[0][nt], 0, 0, 0);
        acc[1][nt] = __builtin_amdgcn_mfma_f32_16x16x32_bf16(pf1, vf, acc[1][nt], 0, 0, 0);
      }
    }
  }

  // epilogue: merge l across q4-groups, normalize, store our d-half
  for (int blk = 0; blk < 2; ++blk) {
    float l = lsum[blk];
    l += __shfl_xor(l, 16);
    l += __shfl_xor(l, 32);
    float rl = 1.f / l;                    // valid for q = c
    float r0 = __shfl(rl, q4 * 4 + 0);
    float r1 = __shfl(rl, q4 * 4 + 1);
    float r2 = __shfl(rl, q4 * 4 + 2);
    float r3 = __shfl(rl, q4 * 4 + 3);
    for (int nt = 0; nt < 4; ++nt) {
      int col = h * H + (db * 4 + nt) * 16 + c;
      int srow = s0 + w * 32 + blk * 16 + q4 * 4;
      ctxbf[(srow + 0) * HD + col] = f2bf(acc[blk][nt][0] * r0);
      ctxbf[(srow + 1) * HD + col] = f2bf(acc[blk][nt][1] * r1);
      ctxbf[(srow + 2) * HD + col] = f2bf(acc[blk][nt][2] * r2);
      ctxbf[(srow + 3) * HD + col] = f2bf(acc[blk][nt][3] * r3);
    }
  }
}

// ---------------- kernel 3: out = ctx @ Wc + bc + x (R5 verbatim) ---------
__global__ __launch_bounds__(256) void out_kernel(
    const unsigned short* __restrict__ ctxbf,
    const unsigned short* __restrict__ WcT,
    const float* __restrict__ bc,
    const float* __restrict__ x,
    float* __restrict__ out)
{
  __shared__ unsigned short At[64 * 136];
  __shared__ unsigned short Bt[128 * 136];
  const int tid = threadIdx.x;
  const int s0 = blockIdx.x * 64;
  const int lane = tid & 63, w = tid >> 6;
  const int c = lane & 15, q4 = lane >> 4;

  f32x4 acc[8];
  for (int nt = 0; nt < 8; ++nt) acc[nt] = (f32x4){0.f, 0.f, 0.f, 0.f};

  for (int kt = 0; kt < 8; ++kt) {
    __syncthreads();
    for (int i = 0; i < 4; ++i) {
      int ch = tid + i * 256;
      int row = ch >> 4, col8 = (ch & 15) * 8;
      *(u16x8*)&At[row * 136 + col8] =
          *(const u16x8*)&ctxbf[(s0 + row) * HD + kt * 128 + col8];
    }
    for (int i = 0; i < 8; ++i) {
      int ch = tid + i * 256;
      int row = ch >> 4, col8 = (ch & 15) * 8;
      *(u16x8*)&Bt[row * 136 + col8] =
          *(const u16x8*)&WcT[row * HD + kt * 128 + col8];
    }
    __syncthreads();
    bf16x8 af[4];
    for (int kc = 0; kc < 4; ++kc)
      af[kc] = ld_bf8(&At[(w * 16 + c) * 136 + kc * 32 + q4 * 8]);
    for (int nt = 0; nt < 8; ++nt) {
      f32x4 a = acc[nt];
      for (int kc = 0; kc < 4; ++kc) {
        bf16x8 bf = ld_bf8(&Bt[(nt * 16 + c) * 136 + kc * 32 + q4 * 8]);
        a = __builtin_amdgcn_mfma_f32_16x16x32_bf16(af[kc], bf, a, 0, 0, 0);
      }
      acc[nt] = a;
    }
  }
  for (int nt = 0; nt < 8; ++nt) {
    float bb = bc[nt * 16 + c];
    for (int r = 0; r < 4; ++r) {
      int srow = s0 + w * 16 + q4 * 4 + r;
      int col = nt * 16 + c;
      out[srow * H + col] = acc[nt][r] + bb + x[srow * H + col];
    }
  }
}

extern "C" void kernel_launch(void* const* d_in, const int* in_sizes, int n_in,
                              void* d_out, int out_size, void* d_ws, size_t ws_size,
                              hipStream_t stream) {
  const float* x  = (const float*)d_in[0];
  const float* W1 = (const float*)d_in[1];
  const float* b1 = (const float*)d_in[2];
  const float* W2 = (const float*)d_in[3];
  const float* b2 = (const float*)d_in[4];
  const float* Wc = (const float*)d_in[5];
  const float* bc = (const float*)d_in[6];
  float* out = (float*)d_out;

  char* ws = (char*)d_ws;
  unsigned short* q1bf = (unsigned short*)ws; ws += (size_t)NHEADS * SQ * H * 2;
  unsigned short* q2K  = (unsigned short*)ws; ws += (size_t)NHEADS * SQ * H * 2;
  unsigned short* q2VT = (unsigned short*)ws; ws += (size_t)NHEADS * SQ * H * 2;
  unsigned short* ctx  = (unsigned short*)ws; ws += (size_t)SQ * HD * 2;
  unsigned short* W1T  = (unsigned short*)ws; ws += (size_t)HD * H * 2;
  unsigned short* W2T  = (unsigned short*)ws; ws += (size_t)HD * H * 2;
  unsigned short* WcT  = (unsigned short*)ws; ws += (size_t)HD * H * 2;

  prep_kernel<<<512, 256, 0, stream>>>(W1, W2, Wc, W1T, W2T, WcT);
  proj_kernel<<<512, 256, 0, stream>>>(x, b1, b2, W1T, W2T, q1bf, q2K, q2VT);
  flash_kernel<<<512, 256, 0, stream>>>(q1bf, q2K, q2VT, ctx);
  out_kernel<<<64, 256, 0, stream>>>(ctx, WcT, bc, x, out);
}

// Round 9
// 228.813 us; speedup vs baseline: 1.0304x; 1.0304x over previous
//
#include <hip/hip_runtime.h>

#define H 128
#define NHEADS 8
#define SQ 4096
#define HD 1024   // NHEADS*H

typedef float f32x4 __attribute__((ext_vector_type(4)));
typedef __bf16 bf16x8 __attribute__((ext_vector_type(8)));
typedef unsigned short u16x4 __attribute__((ext_vector_type(4)));
typedef unsigned short u16x8 __attribute__((ext_vector_type(8)));

static __device__ __forceinline__ unsigned short f2bf(float f) {
  unsigned int u = __builtin_bit_cast(unsigned int, f);
  u += 0x7fffu + ((u >> 16) & 1u);           // round-nearest-even
  return (unsigned short)(u >> 16);
}
static __device__ __forceinline__ float b2f(unsigned short s) {
  unsigned int u = (unsigned int)s << 16;
  return __builtin_bit_cast(float, u);
}
static __device__ __forceinline__ bf16x8 ld_bf8(const unsigned short* p) {
  return __builtin_bit_cast(bf16x8, *(const u16x8*)p);
}

// ---------------- kernel 0: weight transpose+convert (R5 verbatim) --------
__global__ __launch_bounds__(256) void prep_kernel(
    const float* __restrict__ W1, const float* __restrict__ W2,
    const float* __restrict__ Wc,
    unsigned short* __restrict__ W1T, unsigned short* __restrict__ W2T,
    unsigned short* __restrict__ WcT)
{
  int t = blockIdx.x * 256 + threadIdx.x;
  if (t < HD * H) {
    {
      int n = t / H, k = t % H;              // W1/W2 are [128 k][1024 n]
      W1T[t] = f2bf(W1[k * HD + n]);
      W2T[t] = f2bf(W2[k * HD + n]);
    }
    {
      int n = t / HD, k = t % HD;            // Wc is [1024 k][128 n]
      WcT[t] = f2bf(Wc[k * H + n]);
    }
  }
}

// ---------------- kernel 1: q1/q2 projection (R5 verbatim) ----------------
__global__ __launch_bounds__(256) void proj_kernel(
    const float* __restrict__ x,
    const float* __restrict__ b1, const float* __restrict__ b2,
    const unsigned short* __restrict__ W1T, const unsigned short* __restrict__ W2T,
    unsigned short* __restrict__ q1bf, unsigned short* __restrict__ q2K,
    unsigned short* __restrict__ q2VT)
{
  __shared__ unsigned short At[64 * 136];
  __shared__ unsigned short Bt[128 * 136];
  const int tid = threadIdx.x;
  const int st = blockIdx.x & 63, h = blockIdx.x >> 6;
  const int s0 = st * 64;
  const int lane = tid & 63, w = tid >> 6;
  const int c = lane & 15, q4 = lane >> 4;

  for (int i = 0; i < 4; ++i) {
    int ch = tid + i * 256;
    int row = ch >> 4, col8 = (ch & 15) * 8;
    const float* gp = x + (s0 + row) * H + col8;
    f32x4 a = *(const f32x4*)gp;
    f32x4 b = *(const f32x4*)(gp + 4);
    u16x8 v;
    v[0]=f2bf(a[0]); v[1]=f2bf(a[1]); v[2]=f2bf(a[2]); v[3]=f2bf(a[3]);
    v[4]=f2bf(b[0]); v[5]=f2bf(b[1]); v[6]=f2bf(b[2]); v[7]=f2bf(b[3]);
    *(u16x8*)&At[row * 136 + col8] = v;
  }
  for (int i = 0; i < 8; ++i) {
    int ch = tid + i * 256;
    int row = ch >> 4, col8 = (ch & 15) * 8;
    *(u16x8*)&Bt[row * 136 + col8] = *(const u16x8*)&W1T[(h * H + row) * H + col8];
  }
  __syncthreads();

  bf16x8 af[4];
  for (int kc = 0; kc < 4; ++kc)
    af[kc] = ld_bf8(&At[(w * 16 + c) * 136 + kc * 32 + q4 * 8]);

  for (int nt = 0; nt < 8; ++nt) {
    f32x4 acc = {0.f, 0.f, 0.f, 0.f};
    for (int kc = 0; kc < 4; ++kc) {
      bf16x8 bf = ld_bf8(&Bt[(nt * 16 + c) * 136 + kc * 32 + q4 * 8]);
      acc = __builtin_amdgcn_mfma_f32_16x16x32_bf16(af[kc], bf, acc, 0, 0, 0);
    }
    float bb = b1[h * H + nt * 16 + c];
    for (int r = 0; r < 4; ++r) {
      int srow = s0 + w * 16 + q4 * 4 + r;
      q1bf[(h * SQ + srow) * H + nt * 16 + c] = f2bf(acc[r] + bb);
    }
  }
  __syncthreads();
  for (int i = 0; i < 8; ++i) {
    int ch = tid + i * 256;
    int row = ch >> 4, col8 = (ch & 15) * 8;
    *(u16x8*)&Bt[row * 136 + col8] = *(const u16x8*)&W2T[(h * H + row) * H + col8];
  }
  __syncthreads();
  for (int nt = 0; nt < 8; ++nt) {
    f32x4 acc = {0.f, 0.f, 0.f, 0.f};
    for (int kc = 0; kc < 4; ++kc) {
      bf16x8 bf = ld_bf8(&Bt[(nt * 16 + c) * 136 + kc * 32 + q4 * 8]);
      acc = __builtin_amdgcn_mfma_f32_16x16x32_bf16(af[kc], bf, acc, 0, 0, 0);
    }
    float bb = b2[h * H + nt * 16 + c];
    unsigned short vs[4];
    for (int r = 0; r < 4; ++r) {
      int srow = s0 + w * 16 + q4 * 4 + r;
      unsigned short u = f2bf(acc[r] + bb);
      q2K[(h * SQ + srow) * H + nt * 16 + c] = u;
      vs[r] = u;
    }
    u16x4 v4 = {vs[0], vs[1], vs[2], vs[3]};
    *(u16x4*)&q2VT[(h * H + nt * 16 + c) * SQ + s0 + w * 16 + q4 * 4] = v4;
  }
}

// ---------------- kernel 2: flash attention, nkb-way KEY-SPLIT ------------
// grid 256*nkb. nkb==1: EXACTLY the R5-proven kernel (kb=0, 64 tiles, no
// lbuf write). nkb==2: each block does 32 key-tiles, stores locally
// normalized partial O_kb = acc/l_kb plus l_kb (raw-exp softmax -> combine
// exact). Pitches 152/88/72 (all %8==0: b64/b128 DS alignment requirement,
// cf. R6 misalignment failure). LDS 60416 B; 2 blocks/CU fit.
__global__ __launch_bounds__(256) void flash_kernel(
    const unsigned short* __restrict__ q1bf,
    const unsigned short* __restrict__ q2K,
    const unsigned short* __restrict__ q2VT,
    unsigned short* __restrict__ ctxp,   // [kb][s][h*128+d] bf16, local-normed
    float* __restrict__ lbuf,            // [kb][h][s]  (written only if nkb==2)
    int nkb)
{
  __shared__ unsigned short Kt[64 * 152];      // [key][d]  pitch 152
  __shared__ unsigned short VT[128 * 88];      // [d][key]  pitch 88
  __shared__ unsigned short Pb[4][2][16 * 72]; // per-wave/per-qblk [q][key]
  const int tid = threadIdx.x;
  const int bid = blockIdx.x;
  const int kb = bid >> 8;                     // key-half (0 when nkb==1)
  const int h = (bid >> 5) & 7, qb = bid & 31;
  const int s0 = qb * 128;
  const int ntiles = 64 / nkb;
  const int kbase = kb * ntiles * 64;
  const int lane = tid & 63, w = tid >> 6;
  const int c = lane & 15, q4 = lane >> 4;

  // hoist Q B-frags for both q-blocks: B[k = kc*32 + q4*8 + j][n = q = c]
  bf16x8 qf[2][4];
  for (int blk = 0; blk < 2; ++blk)
    for (int kc = 0; kc < 4; ++kc)
      qf[blk][kc] = ld_bf8(
          &q1bf[(h * SQ + s0 + w * 32 + blk * 16 + c) * H + kc * 32 + q4 * 8]);

  f32x4 acc[2][8];
  for (int blk = 0; blk < 2; ++blk)
    for (int nt = 0; nt < 8; ++nt) acc[blk][nt] = (f32x4){0.f, 0.f, 0.f, 0.f};
  float lsum[2] = {0.f, 0.f};

  // prefetch tile 0 into registers
  u16x8 kreg[4], vreg[4];
  for (int i = 0; i < 4; ++i) {
    int ch = tid + i * 256;
    kreg[i] = *(const u16x8*)&q2K[(h * SQ + kbase + (ch >> 4)) * H + (ch & 15) * 8];
    vreg[i] = *(const u16x8*)&q2VT[(h * H + (ch >> 3)) * SQ + kbase + (ch & 7) * 8];
  }

  for (int kt = 0; kt < ntiles; ++kt) {
    if (kt) __syncthreads();               // prev-iter readers done
    for (int i = 0; i < 4; ++i) {          // regs -> LDS
      int ch = tid + i * 256;
      *(u16x8*)&Kt[(ch >> 4) * 152 + (ch & 15) * 8] = kreg[i];
      *(u16x8*)&VT[(ch >> 3) * 88 + (ch & 7) * 8] = vreg[i];
    }
    __syncthreads();                       // staging visible

    if (kt < ntiles - 1) {                 // prefetch next tile -> regs
      const int k0 = kbase + (kt + 1) * 64;
      for (int i = 0; i < 4; ++i) {
        int ch = tid + i * 256;
        kreg[i] = *(const u16x8*)&q2K[(h * SQ + k0 + (ch >> 4)) * H + (ch & 15) * 8];
        vreg[i] = *(const u16x8*)&q2VT[(h * H + (ch >> 3)) * SQ + k0 + (ch & 7) * 8];
      }
    }

    // S^T = K.Q^T per q-block: C[key = mt*16 + q4*4 + r][q = c]
    f32x4 sc[2][4];
    for (int mt = 0; mt < 4; ++mt) {
      bf16x8 kf[4];
      for (int kc = 0; kc < 4; ++kc)
        kf[kc] = ld_bf8(&Kt[(mt * 16 + c) * 152 + kc * 32 + q4 * 8]);
      for (int blk = 0; blk < 2; ++blk) {
        f32x4 s = {0.f, 0.f, 0.f, 0.f};
        for (int kc = 0; kc < 4; ++kc)
          s = __builtin_amdgcn_mfma_f32_16x16x32_bf16(kf[kc], qf[blk][kc], s, 0, 0, 0);
        sc[blk][mt] = s;
      }
    }

    // p = exp(s); per-lane partial l; write P row-major [q = c][key]
    for (int blk = 0; blk < 2; ++blk) {
      float ts = 0.f;
      for (int mt = 0; mt < 4; ++mt) {
        f32x4 p;
        for (int r = 0; r < 4; ++r) { p[r] = __expf(sc[blk][mt][r]); ts += p[r]; }
        sc[blk][mt] = p;
      }
      lsum[blk] += ts;
      for (int mt = 0; mt < 4; ++mt) {
        u16x4 pv = {f2bf(sc[blk][mt][0]), f2bf(sc[blk][mt][1]),
                    f2bf(sc[blk][mt][2]), f2bf(sc[blk][mt][3])};
        *(u16x4*)&Pb[w][blk][c * 72 + mt * 16 + q4 * 4] = pv;
      }
    }

    // PV: acc[blk][nt] += P[q][key32] . V[key32][d]; vf shared across blks
    for (int kc2 = 0; kc2 < 2; ++kc2) {
      bf16x8 pf0 = ld_bf8(&Pb[w][0][c * 72 + kc2 * 32 + q4 * 8]);
      bf16x8 pf1 = ld_bf8(&Pb[w][1][c * 72 + kc2 * 32 + q4 * 8]);
      for (int nt = 0; nt < 8; ++nt) {
        bf16x8 vf = ld_bf8(&VT[(nt * 16 + c) * 88 + kc2 * 32 + q4 * 8]);
        acc[0][nt] = __builtin_amdgcn_mfma_f32_16x16x32_bf16(pf0, vf, acc[0][nt], 0, 0, 0);
        acc[1][nt] = __builtin_amdgcn_mfma_f32_16x16x32_bf16(pf1, vf, acc[1][nt], 0, 0, 0);
      }
    }
  }

  // epilogue: merge l across q4-groups; store local-normalized O (+ l)
  unsigned short* ctxk = ctxp + (size_t)kb * SQ * HD;
  for (int blk = 0; blk < 2; ++blk) {
    float l = lsum[blk];
    l += __shfl_xor(l, 16);
    l += __shfl_xor(l, 32);
    float rl = 1.f / l;                    // valid for q = c
    if (nkb == 2 && q4 == 0)               // one lane per q-row stores l
      lbuf[(size_t)kb * NHEADS * SQ + h * SQ + s0 + w * 32 + blk * 16 + c] = l;
    float r0 = __shfl(rl, q4 * 4 + 0);
    float r1 = __shfl(rl, q4 * 4 + 1);
    float r2 = __shfl(rl, q4 * 4 + 2);
    float r3 = __shfl(rl, q4 * 4 + 3);
    for (int nt = 0; nt < 8; ++nt) {
      int col = h * H + nt * 16 + c;
      int srow = s0 + w * 32 + blk * 16 + q4 * 4;
      ctxk[(size_t)(srow + 0) * HD + col] = f2bf(acc[blk][nt][0] * r0);
      ctxk[(size_t)(srow + 1) * HD + col] = f2bf(acc[blk][nt][1] * r1);
      ctxk[(size_t)(srow + 2) * HD + col] = f2bf(acc[blk][nt][2] * r2);
      ctxk[(size_t)(srow + 3) * HD + col] = f2bf(acc[blk][nt][3] * r3);
    }
  }
}

// ---------------- kernel 3: out = combine(ctxp) @ Wc + bc + x -------------
// R5-proven grid-64 structure. The ONLY change: when nkb==2 the A-tile
// staging combines the two key-half partials. k-block kt covers exactly
// head kt, so the weights are two scalar loads per row:
//   A[row][k] = (la*O0 + lb*O1) / (la+lb),  la = lbuf[0][kt][s0+row].
__global__ __launch_bounds__(256) void out_kernel(
    const unsigned short* __restrict__ ctxp,
    const float* __restrict__ lbuf,
    const unsigned short* __restrict__ WcT,
    const float* __restrict__ bc,
    const float* __restrict__ x,
    float* __restrict__ out,
    int nkb)
{
  __shared__ unsigned short At[64 * 136];
  __shared__ unsigned short Bt[128 * 136];
  const int tid = threadIdx.x;
  const int s0 = blockIdx.x * 64;
  const int lane = tid & 63, w = tid >> 6;
  const int c = lane & 15, q4 = lane >> 4;

  f32x4 acc[8];
  for (int nt = 0; nt < 8; ++nt) acc[nt] = (f32x4){0.f, 0.f, 0.f, 0.f};

  for (int kt = 0; kt < 8; ++kt) {         // head kt
    __syncthreads();
    for (int i = 0; i < 4; ++i) {
      int ch = tid + i * 256;
      int row = ch >> 4, col8 = (ch & 15) * 8;
      const unsigned short* p0 = &ctxp[(size_t)(s0 + row) * HD + kt * 128 + col8];
      u16x8 a0 = *(const u16x8*)p0;
      u16x8 av = a0;
      if (nkb == 2) {
        u16x8 a1 = *(const u16x8*)(p0 + (size_t)SQ * HD);
        float la = lbuf[(size_t)kt * SQ + s0 + row];
        float lb = lbuf[(size_t)NHEADS * SQ + (size_t)kt * SQ + s0 + row];
        float ri = 1.f / (la + lb);
        float wa = la * ri, wb = lb * ri;
        for (int e = 0; e < 8; ++e)
          av[e] = f2bf(wa * b2f(a0[e]) + wb * b2f(a1[e]));
      }
      *(u16x8*)&At[row * 136 + col8] = av;
    }
    for (int i = 0; i < 8; ++i) {
      int ch = tid + i * 256;
      int row = ch >> 4, col8 = (ch & 15) * 8;
      *(u16x8*)&Bt[row * 136 + col8] =
          *(const u16x8*)&WcT[row * HD + kt * 128 + col8];
    }
    __syncthreads();
    bf16x8 af[4];
    for (int kc = 0; kc < 4; ++kc)
      af[kc] = ld_bf8(&At[(w * 16 + c) * 136 + kc * 32 + q4 * 8]);
    for (int nt = 0; nt < 8; ++nt) {
      f32x4 a = acc[nt];
      for (int kc = 0; kc < 4; ++kc) {
        bf16x8 bf = ld_bf8(&Bt[(nt * 16 + c) * 136 + kc * 32 + q4 * 8]);
        a = __builtin_amdgcn_mfma_f32_16x16x32_bf16(af[kc], bf, a, 0, 0, 0);
      }
      acc[nt] = a;
    }
  }
  for (int nt = 0; nt < 8; ++nt) {
    float bb = bc[nt * 16 + c];
    for (int r = 0; r < 4; ++r) {
      int srow = s0 + w * 16 + q4 * 4 + r;
      int col = nt * 16 + c;
      out[srow * H + col] = acc[nt][r] + bb + x[srow * H + col];
    }
  }
}

extern "C" void kernel_launch(void* const* d_in, const int* in_sizes, int n_in,
                              void* d_out, int out_size, void* d_ws, size_t ws_size,
                              hipStream_t stream) {
  const float* x  = (const float*)d_in[0];
  const float* W1 = (const float*)d_in[1];
  const float* b1 = (const float*)d_in[2];
  const float* W2 = (const float*)d_in[3];
  const float* b2 = (const float*)d_in[4];
  const float* Wc = (const float*)d_in[5];
  const float* bc = (const float*)d_in[6];
  float* out = (float*)d_out;

  // key-split (nkb=2) needs 42,991,616 B; fallback (nkb=1, R5-proven) needs
  // 34,340,864 B (R5 passed => available). ws_size is launch-invariant, so
  // nkb is constant across calls (graph-capture safe).
  const size_t NEED2 = (size_t)3 * NHEADS * SQ * H * 2     // q1bf,q2K,q2VT
                     + (size_t)2 * SQ * HD * 2             // ctxp x2
                     + (size_t)2 * NHEADS * SQ * 4         // lbuf x2
                     + (size_t)3 * HD * H * 2;             // W1T,W2T,WcT
  const int nkb = (ws_size >= NEED2) ? 2 : 1;

  char* ws = (char*)d_ws;
  unsigned short* q1bf = (unsigned short*)ws; ws += (size_t)NHEADS * SQ * H * 2;
  unsigned short* q2K  = (unsigned short*)ws; ws += (size_t)NHEADS * SQ * H * 2;
  unsigned short* q2VT = (unsigned short*)ws; ws += (size_t)NHEADS * SQ * H * 2;
  unsigned short* ctxp = (unsigned short*)ws; ws += (size_t)nkb * SQ * HD * 2;
  float*          lbuf = (float*)ws;
  if (nkb == 2)                               ws += (size_t)2 * NHEADS * SQ * 4;
  unsigned short* W1T  = (unsigned short*)ws; ws += (size_t)HD * H * 2;
  unsigned short* W2T  = (unsigned short*)ws; ws += (size_t)HD * H * 2;
  unsigned short* WcT  = (unsigned short*)ws; ws += (size_t)HD * H * 2;

  prep_kernel<<<512, 256, 0, stream>>>(W1, W2, Wc, W1T, W2T, WcT);
  proj_kernel<<<512, 256, 0, stream>>>(x, b1, b2, W1T, W2T, q1bf, q2K, q2VT);
  flash_kernel<<<256 * nkb, 256, 0, stream>>>(q1bf, q2K, q2VT, ctxp, lbuf, nkb);
  out_kernel<<<64, 256, 0, stream>>>(ctxp, lbuf, WcT, bc, x, out, nkb);
}

// Round 10
// 208.153 us; speedup vs baseline: 1.1327x; 1.0993x over previous
//
#include <hip/hip_runtime.h>

#define H 128
#define NHEADS 8
#define SQ 4096
#define HD 1024   // NHEADS*H

typedef float f32x4 __attribute__((ext_vector_type(4)));
typedef __bf16 bf16x8 __attribute__((ext_vector_type(8)));
typedef unsigned short u16x4 __attribute__((ext_vector_type(4)));
typedef unsigned short u16x8 __attribute__((ext_vector_type(8)));

static __device__ __forceinline__ unsigned short f2bf(float f) {
  unsigned int u = __builtin_bit_cast(unsigned int, f);
  u += 0x7fffu + ((u >> 16) & 1u);           // round-nearest-even
  return (unsigned short)(u >> 16);
}
static __device__ __forceinline__ float b2f(unsigned short s) {
  unsigned int u = (unsigned int)s << 16;
  return __builtin_bit_cast(float, u);
}
static __device__ __forceinline__ bf16x8 ld_bf8(const unsigned short* p) {
  return __builtin_bit_cast(bf16x8, *(const u16x8*)p);
}

// ---------------- kernel 0: weight transpose+convert (R5 verbatim) --------
__global__ __launch_bounds__(256) void prep_kernel(
    const float* __restrict__ W1, const float* __restrict__ W2,
    const float* __restrict__ Wc,
    unsigned short* __restrict__ W1T, unsigned short* __restrict__ W2T,
    unsigned short* __restrict__ WcT)
{
  int t = blockIdx.x * 256 + threadIdx.x;
  if (t < HD * H) {
    {
      int n = t / H, k = t % H;              // W1/W2 are [128 k][1024 n]
      W1T[t] = f2bf(W1[k * HD + n]);
      W2T[t] = f2bf(W2[k * HD + n]);
    }
    {
      int n = t / HD, k = t % HD;            // Wc is [1024 k][128 n]
      WcT[t] = f2bf(Wc[k * H + n]);
    }
  }
}

// ---------------- kernel 1: q1/q2 projection (R5 verbatim) ----------------
__global__ __launch_bounds__(256) void proj_kernel(
    const float* __restrict__ x,
    const float* __restrict__ b1, const float* __restrict__ b2,
    const unsigned short* __restrict__ W1T, const unsigned short* __restrict__ W2T,
    unsigned short* __restrict__ q1bf, unsigned short* __restrict__ q2K,
    unsigned short* __restrict__ q2VT)
{
  __shared__ unsigned short At[64 * 136];
  __shared__ unsigned short Bt[128 * 136];
  const int tid = threadIdx.x;
  const int st = blockIdx.x & 63, h = blockIdx.x >> 6;
  const int s0 = st * 64;
  const int lane = tid & 63, w = tid >> 6;
  const int c = lane & 15, q4 = lane >> 4;

  for (int i = 0; i < 4; ++i) {
    int ch = tid + i * 256;
    int row = ch >> 4, col8 = (ch & 15) * 8;
    const float* gp = x + (s0 + row) * H + col8;
    f32x4 a = *(const f32x4*)gp;
    f32x4 b = *(const f32x4*)(gp + 4);
    u16x8 v;
    v[0]=f2bf(a[0]); v[1]=f2bf(a[1]); v[2]=f2bf(a[2]); v[3]=f2bf(a[3]);
    v[4]=f2bf(b[0]); v[5]=f2bf(b[1]); v[6]=f2bf(b[2]); v[7]=f2bf(b[3]);
    *(u16x8*)&At[row * 136 + col8] = v;
  }
  for (int i = 0; i < 8; ++i) {
    int ch = tid + i * 256;
    int row = ch >> 4, col8 = (ch & 15) * 8;
    *(u16x8*)&Bt[row * 136 + col8] = *(const u16x8*)&W1T[(h * H + row) * H + col8];
  }
  __syncthreads();

  bf16x8 af[4];
  for (int kc = 0; kc < 4; ++kc)
    af[kc] = ld_bf8(&At[(w * 16 + c) * 136 + kc * 32 + q4 * 8]);

  for (int nt = 0; nt < 8; ++nt) {
    f32x4 acc = {0.f, 0.f, 0.f, 0.f};
    for (int kc = 0; kc < 4; ++kc) {
      bf16x8 bf = ld_bf8(&Bt[(nt * 16 + c) * 136 + kc * 32 + q4 * 8]);
      acc = __builtin_amdgcn_mfma_f32_16x16x32_bf16(af[kc], bf, acc, 0, 0, 0);
    }
    float bb = b1[h * H + nt * 16 + c];
    for (int r = 0; r < 4; ++r) {
      int srow = s0 + w * 16 + q4 * 4 + r;
      q1bf[(h * SQ + srow) * H + nt * 16 + c] = f2bf(acc[r] + bb);
    }
  }
  __syncthreads();
  for (int i = 0; i < 8; ++i) {
    int ch = tid + i * 256;
    int row = ch >> 4, col8 = (ch & 15) * 8;
    *(u16x8*)&Bt[row * 136 + col8] = *(const u16x8*)&W2T[(h * H + row) * H + col8];
  }
  __syncthreads();
  for (int nt = 0; nt < 8; ++nt) {
    f32x4 acc = {0.f, 0.f, 0.f, 0.f};
    for (int kc = 0; kc < 4; ++kc) {
      bf16x8 bf = ld_bf8(&Bt[(nt * 16 + c) * 136 + kc * 32 + q4 * 8]);
      acc = __builtin_amdgcn_mfma_f32_16x16x32_bf16(af[kc], bf, acc, 0, 0, 0);
    }
    float bb = b2[h * H + nt * 16 + c];
    unsigned short vs[4];
    for (int r = 0; r < 4; ++r) {
      int srow = s0 + w * 16 + q4 * 4 + r;
      unsigned short u = f2bf(acc[r] + bb);
      q2K[(h * SQ + srow) * H + nt * 16 + c] = u;
      vs[r] = u;
    }
    u16x4 v4 = {vs[0], vs[1], vs[2], vs[3]};
    *(u16x4*)&q2VT[(h * H + nt * 16 + c) * SQ + s0 + w * 16 + q4 * 4] = v4;
  }
}

// ---------------- kernel 2: flash attention, 2-way KEY-SPLIT --------------
// grid 512 = kb(2) x 8 heads x 32 q-blocks of 128 rows. Validated in R9
// (nkb==2 path passed, absmax 0.0156). R9 ran at 1 block/CU (Occ 11%,
// 2 sequential rounds of 256 = 135 us): VGPR 136 + runtime-nkb pressure
// blocked co-residency (R7 @ VGPR 116, same LDS, got 2 blocks/CU).
// This round: __launch_bounds__(256, 2) contracts the compiler to a
// 2-waves/EU register budget (<=256 unified regs/wave; we need ~204), and
// NKB is a compile-time constant. No numeric/layout changes vs R9.
// Pitches 152/88/72 (%8==0: ds b64/b128 alignment -- R6 lesson).
__global__ __launch_bounds__(256, 2) void flash_kernel(
    const unsigned short* __restrict__ q1bf,
    const unsigned short* __restrict__ q2K,
    const unsigned short* __restrict__ q2VT,
    unsigned short* __restrict__ ctxp,   // [kb][s][h*128+d] bf16, local-normed
    float* __restrict__ lbuf)            // [kb][h][s]
{
  __shared__ unsigned short Kt[64 * 152];      // [key][d]  pitch 152
  __shared__ unsigned short VT[128 * 88];      // [d][key]  pitch 88
  __shared__ unsigned short Pb[4][2][16 * 72]; // per-wave/per-qblk [q][key]
  const int tid = threadIdx.x;
  const int bid = blockIdx.x;
  const int kb = bid >> 8;                     // key half
  const int h = (bid >> 5) & 7, qb = bid & 31;
  const int s0 = qb * 128;
  const int kbase = kb * 2048;                 // 32 tiles each
  const int lane = tid & 63, w = tid >> 6;
  const int c = lane & 15, q4 = lane >> 4;

  // hoist Q B-frags for both q-blocks: B[k = kc*32 + q4*8 + j][n = q = c]
  bf16x8 qf[2][4];
  for (int blk = 0; blk < 2; ++blk)
    for (int kc = 0; kc < 4; ++kc)
      qf[blk][kc] = ld_bf8(
          &q1bf[(h * SQ + s0 + w * 32 + blk * 16 + c) * H + kc * 32 + q4 * 8]);

  f32x4 acc[2][8];
  for (int blk = 0; blk < 2; ++blk)
    for (int nt = 0; nt < 8; ++nt) acc[blk][nt] = (f32x4){0.f, 0.f, 0.f, 0.f};
  float lsum[2] = {0.f, 0.f};

  // prefetch tile 0 into registers
  u16x8 kreg[4], vreg[4];
  for (int i = 0; i < 4; ++i) {
    int ch = tid + i * 256;
    kreg[i] = *(const u16x8*)&q2K[(h * SQ + kbase + (ch >> 4)) * H + (ch & 15) * 8];
    vreg[i] = *(const u16x8*)&q2VT[(h * H + (ch >> 3)) * SQ + kbase + (ch & 7) * 8];
  }

  for (int kt = 0; kt < 32; ++kt) {
    if (kt) __syncthreads();               // prev-iter readers done
    for (int i = 0; i < 4; ++i) {          // regs -> LDS
      int ch = tid + i * 256;
      *(u16x8*)&Kt[(ch >> 4) * 152 + (ch & 15) * 8] = kreg[i];
      *(u16x8*)&VT[(ch >> 3) * 88 + (ch & 7) * 8] = vreg[i];
    }
    __syncthreads();                       // staging visible

    if (kt < 31) {                         // prefetch next tile -> regs
      const int k0 = kbase + (kt + 1) * 64;
      for (int i = 0; i < 4; ++i) {
        int ch = tid + i * 256;
        kreg[i] = *(const u16x8*)&q2K[(h * SQ + k0 + (ch >> 4)) * H + (ch & 15) * 8];
        vreg[i] = *(const u16x8*)&q2VT[(h * H + (ch >> 3)) * SQ + k0 + (ch & 7) * 8];
      }
    }

    // S^T = K.Q^T per q-block: C[key = mt*16 + q4*4 + r][q = c]
    f32x4 sc[2][4];
    for (int mt = 0; mt < 4; ++mt) {
      bf16x8 kf[4];
      for (int kc = 0; kc < 4; ++kc)
        kf[kc] = ld_bf8(&Kt[(mt * 16 + c) * 152 + kc * 32 + q4 * 8]);
      for (int blk = 0; blk < 2; ++blk) {
        f32x4 s = {0.f, 0.f, 0.f, 0.f};
        for (int kc = 0; kc < 4; ++kc)
          s = __builtin_amdgcn_mfma_f32_16x16x32_bf16(kf[kc], qf[blk][kc], s, 0, 0, 0);
        sc[blk][mt] = s;
      }
    }

    // p = exp(s); per-lane partial l; write P row-major [q = c][key]
    for (int blk = 0; blk < 2; ++blk) {
      float ts = 0.f;
      for (int mt = 0; mt < 4; ++mt) {
        f32x4 p;
        for (int r = 0; r < 4; ++r) { p[r] = __expf(sc[blk][mt][r]); ts += p[r]; }
        sc[blk][mt] = p;
      }
      lsum[blk] += ts;
      for (int mt = 0; mt < 4; ++mt) {
        u16x4 pv = {f2bf(sc[blk][mt][0]), f2bf(sc[blk][mt][1]),
                    f2bf(sc[blk][mt][2]), f2bf(sc[blk][mt][3])};
        *(u16x4*)&Pb[w][blk][c * 72 + mt * 16 + q4 * 4] = pv;
      }
    }

    // PV: acc[blk][nt] += P[q][key32] . V[key32][d]; vf shared across blks
    for (int kc2 = 0; kc2 < 2; ++kc2) {
      bf16x8 pf0 = ld_bf8(&Pb[w][0][c * 72 + kc2 * 32 + q4 * 8]);
      bf16x8 pf1 = ld_bf8(&Pb[w][1][c * 72 + kc2 * 32 + q4 * 8]);
      for (int nt = 0; nt < 8; ++nt) {
        bf16x8 vf = ld_bf8(&VT[(nt * 16 + c) * 88 + kc2 * 32 + q4 * 8]);
        acc[0][nt] = __builtin_amdgcn_mfma_f32_16x16x32_bf16(pf0, vf, acc[0][nt], 0, 0, 0);
        acc[1][nt] = __builtin_amdgcn_mfma_f32_16x16x32_bf16(pf1, vf, acc[1][nt], 0, 0, 0);
      }
    }
  }

  // epilogue: merge l across q4-groups; store local-normalized O + l
  unsigned short* ctxk = ctxp + (size_t)kb * SQ * HD;
  for (int blk = 0; blk < 2; ++blk) {
    float l = lsum[blk];
    l += __shfl_xor(l, 16);
    l += __shfl_xor(l, 32);
    float rl = 1.f / l;                    // valid for q = c
    if (q4 == 0)                           // one lane per q-row stores l
      lbuf[(size_t)kb * NHEADS * SQ + h * SQ + s0 + w * 32 + blk * 16 + c] = l;
    float r0 = __shfl(rl, q4 * 4 + 0);
    float r1 = __shfl(rl, q4 * 4 + 1);
    float r2 = __shfl(rl, q4 * 4 + 2);
    float r3 = __shfl(rl, q4 * 4 + 3);
    for (int nt = 0; nt < 8; ++nt) {
      int col = h * H + nt * 16 + c;
      int srow = s0 + w * 32 + blk * 16 + q4 * 4;
      ctxk[(size_t)(srow + 0) * HD + col] = f2bf(acc[blk][nt][0] * r0);
      ctxk[(size_t)(srow + 1) * HD + col] = f2bf(acc[blk][nt][1] * r1);
      ctxk[(size_t)(srow + 2) * HD + col] = f2bf(acc[blk][nt][2] * r2);
      ctxk[(size_t)(srow + 3) * HD + col] = f2bf(acc[blk][nt][3] * r3);
    }
  }
}

// ---------------- kernel 3: out = combine(ctxp) @ Wc + bc + x -------------
// R9-VALIDATED: grid-64 R5 structure; A-tile staging combines the two
// key-half partials (head kt => two scalar l-loads per row; exact for
// raw-exp softmax).
__global__ __launch_bounds__(256) void out_kernel(
    const unsigned short* __restrict__ ctxp,
    const float* __restrict__ lbuf,
    const unsigned short* __restrict__ WcT,
    const float* __restrict__ bc,
    const float* __restrict__ x,
    float* __restrict__ out)
{
  __shared__ unsigned short At[64 * 136];
  __shared__ unsigned short Bt[128 * 136];
  const int tid = threadIdx.x;
  const int s0 = blockIdx.x * 64;
  const int lane = tid & 63, w = tid >> 6;
  const int c = lane & 15, q4 = lane >> 4;

  f32x4 acc[8];
  for (int nt = 0; nt < 8; ++nt) acc[nt] = (f32x4){0.f, 0.f, 0.f, 0.f};

  for (int kt = 0; kt < 8; ++kt) {         // head kt
    __syncthreads();
    for (int i = 0; i < 4; ++i) {
      int ch = tid + i * 256;
      int row = ch >> 4, col8 = (ch & 15) * 8;
      const unsigned short* p0 = &ctxp[(size_t)(s0 + row) * HD + kt * 128 + col8];
      u16x8 a0 = *(const u16x8*)p0;
      u16x8 a1 = *(const u16x8*)(p0 + (size_t)SQ * HD);
      float la = lbuf[(size_t)kt * SQ + s0 + row];
      float lb = lbuf[(size_t)NHEADS * SQ + (size_t)kt * SQ + s0 + row];
      float ri = 1.f / (la + lb);
      float wa = la * ri, wb = lb * ri;
      u16x8 av;
      for (int e = 0; e < 8; ++e)
        av[e] = f2bf(wa * b2f(a0[e]) + wb * b2f(a1[e]));
      *(u16x8*)&At[row * 136 + col8] = av;
    }
    for (int i = 0; i < 8; ++i) {
      int ch = tid + i * 256;
      int row = ch >> 4, col8 = (ch & 15) * 8;
      *(u16x8*)&Bt[row * 136 + col8] =
          *(const u16x8*)&WcT[row * HD + kt * 128 + col8];
    }
    __syncthreads();
    bf16x8 af[4];
    for (int kc = 0; kc < 4; ++kc)
      af[kc] = ld_bf8(&At[(w * 16 + c) * 136 + kc * 32 + q4 * 8]);
    for (int nt = 0; nt < 8; ++nt) {
      f32x4 a = acc[nt];
      for (int kc = 0; kc < 4; ++kc) {
        bf16x8 bf = ld_bf8(&Bt[(nt * 16 + c) * 136 + kc * 32 + q4 * 8]);
        a = __builtin_amdgcn_mfma_f32_16x16x32_bf16(af[kc], bf, a, 0, 0, 0);
      }
      acc[nt] = a;
    }
  }
  for (int nt = 0; nt < 8; ++nt) {
    float bb = bc[nt * 16 + c];
    for (int r = 0; r < 4; ++r) {
      int srow = s0 + w * 16 + q4 * 4 + r;
      int col = nt * 16 + c;
      out[srow * H + col] = acc[nt][r] + bb + x[srow * H + col];
    }
  }
}

extern "C" void kernel_launch(void* const* d_in, const int* in_sizes, int n_in,
                              void* d_out, int out_size, void* d_ws, size_t ws_size,
                              hipStream_t stream) {
  const float* x  = (const float*)d_in[0];
  const float* W1 = (const float*)d_in[1];
  const float* b1 = (const float*)d_in[2];
  const float* W2 = (const float*)d_in[3];
  const float* b2 = (const float*)d_in[4];
  const float* Wc = (const float*)d_in[5];
  const float* bc = (const float*)d_in[6];
  float* out = (float*)d_out;

  // Key-split layout (42,991,616 B) -- capacity proven by R9's passing run.
  char* ws = (char*)d_ws;
  unsigned short* q1bf = (unsigned short*)ws; ws += (size_t)NHEADS * SQ * H * 2;
  unsigned short* q2K  = (unsigned short*)ws; ws += (size_t)NHEADS * SQ * H * 2;
  unsigned short* q2VT = (unsigned short*)ws; ws += (size_t)NHEADS * SQ * H * 2;
  unsigned short* ctxp = (unsigned short*)ws; ws += (size_t)2 * SQ * HD * 2;
  float*          lbuf = (float*)ws;          ws += (size_t)2 * NHEADS * SQ * 4;
  unsigned short* W1T  = (unsigned short*)ws; ws += (size_t)HD * H * 2;
  unsigned short* W2T  = (unsigned short*)ws; ws += (size_t)HD * H * 2;
  unsigned short* WcT  = (unsigned short*)ws; ws += (size_t)HD * H * 2;

  prep_kernel<<<512, 256, 0, stream>>>(W1, W2, Wc, W1T, W2T, WcT);
  proj_kernel<<<512, 256, 0, stream>>>(x, b1, b2, W1T, W2T, q1bf, q2K, q2VT);
  flash_kernel<<<512, 256, 0, stream>>>(q1bf, q2K, q2VT, ctxp, lbuf);
  out_kernel<<<64, 256, 0, stream>>>(ctxp, lbuf, WcT, bc, x, out);
}

// Round 11
// 207.058 us; speedup vs baseline: 1.1387x; 1.0053x over previous
//
#include <hip/hip_runtime.h>

#define H 128
#define NHEADS 8
#define SQ 4096
#define HD 1024   // NHEADS*H

typedef float f32x4 __attribute__((ext_vector_type(4)));
typedef __bf16 bf16x8 __attribute__((ext_vector_type(8)));
typedef unsigned short u16x4 __attribute__((ext_vector_type(4)));
typedef unsigned short u16x8 __attribute__((ext_vector_type(8)));

static __device__ __forceinline__ unsigned short f2bf(float f) {
  unsigned int u = __builtin_bit_cast(unsigned int, f);
  u += 0x7fffu + ((u >> 16) & 1u);           // round-nearest-even
  return (unsigned short)(u >> 16);
}
static __device__ __forceinline__ float b2f(unsigned short s) {
  unsigned int u = (unsigned int)s << 16;
  return __builtin_bit_cast(float, u);
}
static __device__ __forceinline__ bf16x8 ld_bf8(const unsigned short* p) {
  return __builtin_bit_cast(bf16x8, *(const u16x8*)p);
}

// ---------------- kernel 0: weight transpose+convert, LDS-tiled -----------
// grid 64. Blocks 0..31: W1+W2 ([128 k][1024 n] -> [n][k]); 32..63: Wc
// ([1024 k][128 n] -> [n][k]). 64x64 tiles; pitch 66 shorts (odd dword) so
// the transpose scatter phase is conflict-free. All global reads AND writes
// coalesced (R10 prep did 1.5M scalar loads at 4 KB stride: ~15-20 us).
__global__ __launch_bounds__(256) void prep_kernel(
    const float* __restrict__ W1, const float* __restrict__ W2,
    const float* __restrict__ Wc,
    unsigned short* __restrict__ W1T, unsigned short* __restrict__ W2T,
    unsigned short* __restrict__ WcT)
{
  __shared__ unsigned short tile[64 * 66];
  const int b = blockIdx.x, tid = threadIdx.x;
  if (b < 32) {
    const int k0 = (b & 1) * 64, n0 = (b >> 1) * 64;
    for (int i = 0; i < 16; ++i) {
      int idx = tid + i * 256;
      int r = idx >> 6, cc = idx & 63;       // r = k-local, cc = n-local
      tile[cc * 66 + r] = f2bf(W1[(size_t)(k0 + r) * HD + n0 + cc]);
    }
    __syncthreads();
    for (int i = 0; i < 16; ++i) {
      int idx = tid + i * 256;
      int r = idx >> 6, cc = idx & 63;       // r = n-local, cc = k-local
      W1T[(size_t)(n0 + r) * H + k0 + cc] = tile[r * 66 + cc];
    }
    __syncthreads();
    for (int i = 0; i < 16; ++i) {
      int idx = tid + i * 256;
      int r = idx >> 6, cc = idx & 63;
      tile[cc * 66 + r] = f2bf(W2[(size_t)(k0 + r) * HD + n0 + cc]);
    }
    __syncthreads();
    for (int i = 0; i < 16; ++i) {
      int idx = tid + i * 256;
      int r = idx >> 6, cc = idx & 63;
      W2T[(size_t)(n0 + r) * H + k0 + cc] = tile[r * 66 + cc];
    }
  } else {
    const int bb = b - 32;
    const int n0 = (bb & 1) * 64, k0 = (bb >> 1) * 64;
    for (int i = 0; i < 16; ++i) {
      int idx = tid + i * 256;
      int r = idx >> 6, cc = idx & 63;       // r = k-local, cc = n-local
      tile[cc * 66 + r] = f2bf(Wc[(size_t)(k0 + r) * H + n0 + cc]);
    }
    __syncthreads();
    for (int i = 0; i < 16; ++i) {
      int idx = tid + i * 256;
      int r = idx >> 6, cc = idx & 63;       // r = n-local, cc = k-local
      WcT[(size_t)(n0 + r) * HD + k0 + cc] = tile[r * 66 + cc];
    }
  }
}

// ---------------- kernel 1: q1/q2 projection, coalesced stores ------------
// Same MFMA/numerics as R10 (values bit-identical). All outputs now staged
// through reused At/Bt LDS tiles and written as u16x8 (q1bf/q2K: 256 B/row;
// q2VT: 128 B/row) instead of R10's 2-8 B scattered granules.
__global__ __launch_bounds__(256) void proj_kernel(
    const float* __restrict__ x,
    const float* __restrict__ b1, const float* __restrict__ b2,
    const unsigned short* __restrict__ W1T, const unsigned short* __restrict__ W2T,
    unsigned short* __restrict__ q1bf, unsigned short* __restrict__ q2K,
    unsigned short* __restrict__ q2VT)
{
  __shared__ unsigned short At[64 * 136];
  __shared__ unsigned short Bt[128 * 136];
  const int tid = threadIdx.x;
  const int st = blockIdx.x & 63, h = blockIdx.x >> 6;
  const int s0 = st * 64;
  const int lane = tid & 63, w = tid >> 6;
  const int c = lane & 15, q4 = lane >> 4;

  // stage x tile (fp32 -> bf16) and W1T head slice
  for (int i = 0; i < 4; ++i) {
    int ch = tid + i * 256;
    int row = ch >> 4, col8 = (ch & 15) * 8;
    const float* gp = x + (s0 + row) * H + col8;
    f32x4 a = *(const f32x4*)gp;
    f32x4 b = *(const f32x4*)(gp + 4);
    u16x8 v;
    v[0]=f2bf(a[0]); v[1]=f2bf(a[1]); v[2]=f2bf(a[2]); v[3]=f2bf(a[3]);
    v[4]=f2bf(b[0]); v[5]=f2bf(b[1]); v[6]=f2bf(b[2]); v[7]=f2bf(b[3]);
    *(u16x8*)&At[row * 136 + col8] = v;
  }
  for (int i = 0; i < 8; ++i) {
    int ch = tid + i * 256;
    int row = ch >> 4, col8 = (ch & 15) * 8;
    *(u16x8*)&Bt[row * 136 + col8] = *(const u16x8*)&W1T[(h * H + row) * H + col8];
  }
  __syncthreads();                           // S1

  bf16x8 af[4];                              // A-frags (reused for q1 and q2)
  for (int kc = 0; kc < 4; ++kc)
    af[kc] = ld_bf8(&At[(w * 16 + c) * 136 + kc * 32 + q4 * 8]);
  __syncthreads();                           // S2: all af hoisted; At reusable

  // q1 = x @ W1 + b1 -> stage into At as [s-local][d]
  for (int nt = 0; nt < 8; ++nt) {
    f32x4 acc = {0.f, 0.f, 0.f, 0.f};
    for (int kc = 0; kc < 4; ++kc) {
      bf16x8 bf = ld_bf8(&Bt[(nt * 16 + c) * 136 + kc * 32 + q4 * 8]);
      acc = __builtin_amdgcn_mfma_f32_16x16x32_bf16(af[kc], bf, acc, 0, 0, 0);
    }
    float bb = b1[h * H + nt * 16 + c];
    for (int r = 0; r < 4; ++r)
      At[(w * 16 + q4 * 4 + r) * 136 + nt * 16 + c] = f2bf(acc[r] + bb);
  }
  __syncthreads();                           // S3: q1 tile done; Bt reusable

  // coalesced q1bf store; restage W2T
  for (int i = 0; i < 4; ++i) {
    int ch = tid + i * 256;
    int row = ch >> 4, col8 = (ch & 15) * 8;
    *(u16x8*)&q1bf[(size_t)(h * SQ + s0 + row) * H + col8] =
        *(const u16x8*)&At[row * 136 + col8];
  }
  for (int i = 0; i < 8; ++i) {
    int ch = tid + i * 256;
    int row = ch >> 4, col8 = (ch & 15) * 8;
    *(u16x8*)&Bt[row * 136 + col8] = *(const u16x8*)&W2T[(h * H + row) * H + col8];
  }
  __syncthreads();                           // S4: W2 staged; At reusable

  // q2 = x @ W2 + b2 (accs held in regs)
  f32x4 q2a[8];
  for (int nt = 0; nt < 8; ++nt) {
    f32x4 acc = {0.f, 0.f, 0.f, 0.f};
    for (int kc = 0; kc < 4; ++kc) {
      bf16x8 bf = ld_bf8(&Bt[(nt * 16 + c) * 136 + kc * 32 + q4 * 8]);
      acc = __builtin_amdgcn_mfma_f32_16x16x32_bf16(af[kc], bf, acc, 0, 0, 0);
    }
    q2a[nt] = acc;
  }
  __syncthreads();                           // S5: Bt reads done; reusable

  // scatter q2 into At as [s][d] and Bt (pitch 72) as [d][s]
  for (int nt = 0; nt < 8; ++nt) {
    float bb = b2[h * H + nt * 16 + c];
    unsigned short vs[4];
    for (int r = 0; r < 4; ++r) {
      unsigned short u = f2bf(q2a[nt][r] + bb);
      At[(w * 16 + q4 * 4 + r) * 136 + nt * 16 + c] = u;
      vs[r] = u;
    }
    u16x4 v4 = {vs[0], vs[1], vs[2], vs[3]};
    *(u16x4*)&Bt[(nt * 16 + c) * 72 + w * 16 + q4 * 4] = v4;
  }
  __syncthreads();                           // S6

  // coalesced q2K ([s][d]) and q2VT ([d][s]) stores
  for (int i = 0; i < 4; ++i) {
    int ch = tid + i * 256;
    int row = ch >> 4, col8 = (ch & 15) * 8;
    *(u16x8*)&q2K[(size_t)(h * SQ + s0 + row) * H + col8] =
        *(const u16x8*)&At[row * 136 + col8];
  }
  for (int i = 0; i < 4; ++i) {
    int ch = tid + i * 256;
    int row = ch >> 3, col8 = (ch & 7) * 8;  // row = d 0..127
    *(u16x8*)&q2VT[(size_t)(h * H + row) * SQ + s0 + col8] =
        *(const u16x8*)&Bt[row * 72 + col8];
  }
}

// ---------------- kernel 2: flash attention, 2-way KEY-SPLIT (R10 verbatim)
__global__ __launch_bounds__(256, 2) void flash_kernel(
    const unsigned short* __restrict__ q1bf,
    const unsigned short* __restrict__ q2K,
    const unsigned short* __restrict__ q2VT,
    unsigned short* __restrict__ ctxp,   // [kb][s][h*128+d] bf16, local-normed
    float* __restrict__ lbuf)            // [kb][h][s]
{
  __shared__ unsigned short Kt[64 * 152];      // [key][d]  pitch 152
  __shared__ unsigned short VT[128 * 88];      // [d][key]  pitch 88
  __shared__ unsigned short Pb[4][2][16 * 72]; // per-wave/per-qblk [q][key]
  const int tid = threadIdx.x;
  const int bid = blockIdx.x;
  const int kb = bid >> 8;                     // key half
  const int h = (bid >> 5) & 7, qb = bid & 31;
  const int s0 = qb * 128;
  const int kbase = kb * 2048;                 // 32 tiles each
  const int lane = tid & 63, w = tid >> 6;
  const int c = lane & 15, q4 = lane >> 4;

  bf16x8 qf[2][4];
  for (int blk = 0; blk < 2; ++blk)
    for (int kc = 0; kc < 4; ++kc)
      qf[blk][kc] = ld_bf8(
          &q1bf[(h * SQ + s0 + w * 32 + blk * 16 + c) * H + kc * 32 + q4 * 8]);

  f32x4 acc[2][8];
  for (int blk = 0; blk < 2; ++blk)
    for (int nt = 0; nt < 8; ++nt) acc[blk][nt] = (f32x4){0.f, 0.f, 0.f, 0.f};
  float lsum[2] = {0.f, 0.f};

  u16x8 kreg[4], vreg[4];
  for (int i = 0; i < 4; ++i) {
    int ch = tid + i * 256;
    kreg[i] = *(const u16x8*)&q2K[(h * SQ + kbase + (ch >> 4)) * H + (ch & 15) * 8];
    vreg[i] = *(const u16x8*)&q2VT[(h * H + (ch >> 3)) * SQ + kbase + (ch & 7) * 8];
  }

  for (int kt = 0; kt < 32; ++kt) {
    if (kt) __syncthreads();
    for (int i = 0; i < 4; ++i) {
      int ch = tid + i * 256;
      *(u16x8*)&Kt[(ch >> 4) * 152 + (ch & 15) * 8] = kreg[i];
      *(u16x8*)&VT[(ch >> 3) * 88 + (ch & 7) * 8] = vreg[i];
    }
    __syncthreads();

    if (kt < 31) {
      const int k0 = kbase + (kt + 1) * 64;
      for (int i = 0; i < 4; ++i) {
        int ch = tid + i * 256;
        kreg[i] = *(const u16x8*)&q2K[(h * SQ + k0 + (ch >> 4)) * H + (ch & 15) * 8];
        vreg[i] = *(const u16x8*)&q2VT[(h * H + (ch >> 3)) * SQ + k0 + (ch & 7) * 8];
      }
    }

    f32x4 sc[2][4];
    for (int mt = 0; mt < 4; ++mt) {
      bf16x8 kf[4];
      for (int kc = 0; kc < 4; ++kc)
        kf[kc] = ld_bf8(&Kt[(mt * 16 + c) * 152 + kc * 32 + q4 * 8]);
      for (int blk = 0; blk < 2; ++blk) {
        f32x4 s = {0.f, 0.f, 0.f, 0.f};
        for (int kc = 0; kc < 4; ++kc)
          s = __builtin_amdgcn_mfma_f32_16x16x32_bf16(kf[kc], qf[blk][kc], s, 0, 0, 0);
        sc[blk][mt] = s;
      }
    }

    for (int blk = 0; blk < 2; ++blk) {
      float ts = 0.f;
      for (int mt = 0; mt < 4; ++mt) {
        f32x4 p;
        for (int r = 0; r < 4; ++r) { p[r] = __expf(sc[blk][mt][r]); ts += p[r]; }
        sc[blk][mt] = p;
      }
      lsum[blk] += ts;
      for (int mt = 0; mt < 4; ++mt) {
        u16x4 pv = {f2bf(sc[blk][mt][0]), f2bf(sc[blk][mt][1]),
                    f2bf(sc[blk][mt][2]), f2bf(sc[blk][mt][3])};
        *(u16x4*)&Pb[w][blk][c * 72 + mt * 16 + q4 * 4] = pv;
      }
    }

    for (int kc2 = 0; kc2 < 2; ++kc2) {
      bf16x8 pf0 = ld_bf8(&Pb[w][0][c * 72 + kc2 * 32 + q4 * 8]);
      bf16x8 pf1 = ld_bf8(&Pb[w][1][c * 72 + kc2 * 32 + q4 * 8]);
      for (int nt = 0; nt < 8; ++nt) {
        bf16x8 vf = ld_bf8(&VT[(nt * 16 + c) * 88 + kc2 * 32 + q4 * 8]);
        acc[0][nt] = __builtin_amdgcn_mfma_f32_16x16x32_bf16(pf0, vf, acc[0][nt], 0, 0, 0);
        acc[1][nt] = __builtin_amdgcn_mfma_f32_16x16x32_bf16(pf1, vf, acc[1][nt], 0, 0, 0);
      }
    }
  }

  unsigned short* ctxk = ctxp + (size_t)kb * SQ * HD;
  for (int blk = 0; blk < 2; ++blk) {
    float l = lsum[blk];
    l += __shfl_xor(l, 16);
    l += __shfl_xor(l, 32);
    float rl = 1.f / l;
    if (q4 == 0)
      lbuf[(size_t)kb * NHEADS * SQ + h * SQ + s0 + w * 32 + blk * 16 + c] = l;
    float r0 = __shfl(rl, q4 * 4 + 0);
    float r1 = __shfl(rl, q4 * 4 + 1);
    float r2 = __shfl(rl, q4 * 4 + 2);
    float r3 = __shfl(rl, q4 * 4 + 3);
    for (int nt = 0; nt < 8; ++nt) {
      int col = h * H + nt * 16 + c;
      int srow = s0 + w * 32 + blk * 16 + q4 * 4;
      ctxk[(size_t)(srow + 0) * HD + col] = f2bf(acc[blk][nt][0] * r0);
      ctxk[(size_t)(srow + 1) * HD + col] = f2bf(acc[blk][nt][1] * r1);
      ctxk[(size_t)(srow + 2) * HD + col] = f2bf(acc[blk][nt][2] * r2);
      ctxk[(size_t)(srow + 3) * HD + col] = f2bf(acc[blk][nt][3] * r3);
    }
  }
}

// ---------------- kernel 3: out = combine(ctxp) @ Wc + bc + x (R10 verbatim)
__global__ __launch_bounds__(256) void out_kernel(
    const unsigned short* __restrict__ ctxp,
    const float* __restrict__ lbuf,
    const unsigned short* __restrict__ WcT,
    const float* __restrict__ bc,
    const float* __restrict__ x,
    float* __restrict__ out)
{
  __shared__ unsigned short At[64 * 136];
  __shared__ unsigned short Bt[128 * 136];
  const int tid = threadIdx.x;
  const int s0 = blockIdx.x * 64;
  const int lane = tid & 63, w = tid >> 6;
  const int c = lane & 15, q4 = lane >> 4;

  f32x4 acc[8];
  for (int nt = 0; nt < 8; ++nt) acc[nt] = (f32x4){0.f, 0.f, 0.f, 0.f};

  for (int kt = 0; kt < 8; ++kt) {         // head kt
    __syncthreads();
    for (int i = 0; i < 4; ++i) {
      int ch = tid + i * 256;
      int row = ch >> 4, col8 = (ch & 15) * 8;
      const unsigned short* p0 = &ctxp[(size_t)(s0 + row) * HD + kt * 128 + col8];
      u16x8 a0 = *(const u16x8*)p0;
      u16x8 a1 = *(const u16x8*)(p0 + (size_t)SQ * HD);
      float la = lbuf[(size_t)kt * SQ + s0 + row];
      float lb = lbuf[(size_t)NHEADS * SQ + (size_t)kt * SQ + s0 + row];
      float ri = 1.f / (la + lb);
      float wa = la * ri, wb = lb * ri;
      u16x8 av;
      for (int e = 0; e < 8; ++e)
        av[e] = f2bf(wa * b2f(a0[e]) + wb * b2f(a1[e]));
      *(u16x8*)&At[row * 136 + col8] = av;
    }
    for (int i = 0; i < 8; ++i) {
      int ch = tid + i * 256;
      int row = ch >> 4, col8 = (ch & 15) * 8;
      *(u16x8*)&Bt[row * 136 + col8] =
          *(const u16x8*)&WcT[row * HD + kt * 128 + col8];
    }
    __syncthreads();
    bf16x8 af[4];
    for (int kc = 0; kc < 4; ++kc)
      af[kc] = ld_bf8(&At[(w * 16 + c) * 136 + kc * 32 + q4 * 8]);
    for (int nt = 0; nt < 8; ++nt) {
      f32x4 a = acc[nt];
      for (int kc = 0; kc < 4; ++kc) {
        bf16x8 bf = ld_bf8(&Bt[(nt * 16 + c) * 136 + kc * 32 + q4 * 8]);
        a = __builtin_amdgcn_mfma_f32_16x16x32_bf16(af[kc], bf, a, 0, 0, 0);
      }
      acc[nt] = a;
    }
  }
  for (int nt = 0; nt < 8; ++nt) {
    float bb = bc[nt * 16 + c];
    for (int r = 0; r < 4; ++r) {
      int srow = s0 + w * 16 + q4 * 4 + r;
      int col = nt * 16 + c;
      out[srow * H + col] = acc[nt][r] + bb + x[srow * H + col];
    }
  }
}

extern "C" void kernel_launch(void* const* d_in, const int* in_sizes, int n_in,
                              void* d_out, int out_size, void* d_ws, size_t ws_size,
                              hipStream_t stream) {
  const float* x  = (const float*)d_in[0];
  const float* W1 = (const float*)d_in[1];
  const float* b1 = (const float*)d_in[2];
  const float* W2 = (const float*)d_in[3];
  const float* b2 = (const float*)d_in[4];
  const float* Wc = (const float*)d_in[5];
  const float* bc = (const float*)d_in[6];
  float* out = (float*)d_out;

  // Key-split layout (42,991,616 B) -- capacity proven by R9/R10 passes.
  char* ws = (char*)d_ws;
  unsigned short* q1bf = (unsigned short*)ws; ws += (size_t)NHEADS * SQ * H * 2;
  unsigned short* q2K  = (unsigned short*)ws; ws += (size_t)NHEADS * SQ * H * 2;
  unsigned short* q2VT = (unsigned short*)ws; ws += (size_t)NHEADS * SQ * H * 2;
  unsigned short* ctxp = (unsigned short*)ws; ws += (size_t)2 * SQ * HD * 2;
  float*          lbuf = (float*)ws;          ws += (size_t)2 * NHEADS * SQ * 4;
  unsigned short* W1T  = (unsigned short*)ws; ws += (size_t)HD * H * 2;
  unsigned short* W2T  = (unsigned short*)ws; ws += (size_t)HD * H * 2;
  unsigned short* WcT  = (unsigned short*)ws; ws += (size_t)HD * H * 2;

  prep_kernel<<<64, 256, 0, stream>>>(W1, W2, Wc, W1T, W2T, WcT);
  proj_kernel<<<512, 256, 0, stream>>>(x, b1, b2, W1T, W2T, q1bf, q2K, q2VT);
  flash_kernel<<<512, 256, 0, stream>>>(q1bf, q2K, q2VT, ctxp, lbuf);
  out_kernel<<<64, 256, 0, stream>>>(ctxp, lbuf, WcT, bc, x, out);
}